// Round 1
// baseline (287.907 us; speedup 1.0000x reference)
//
#include <hip/hip_runtime.h>

#define DIM 6
#define NSTATE 1554      // 6 + 36 + 216 + 1296
#define STRIDE 1568      // padded state buffer stride
#define ONE_SLOT 1554    // holds 1.0f in both state buffers
#define DUMMY_SLOT 1555  // write sink for inactive slots
#define ZERO_SLOT 1556   // holds 0.0f always
#define CHUNK 64
#define NSEG 65535
#define NCHUNK 1024      // NCHUNK*CHUNK >= NSEG
#define NSLOT 7          // ceil(1554/256)

// Z scratch layout (per-segment helpers)
#define Z_E2 0    // 36: e2[cd] = dx_c*dx_d/2
#define Z_T2 36   // 36: t2[ab] = S2[ab] + dx_b*(S1[a]/3 + dx_a/12)
#define Z_T3 72   // 6:  t3[a]  = S1[a] + dx_a/3
#define Z_DX 78   // 6:  dx
#define Z_ONE 84
#define Z_ZERO 85

// ---------------- Kernel A: per-chunk signature via sequential Chen fold ----
__global__ __launch_bounds__(256) void sig_chunks(const float* __restrict__ x,
                                                  float* __restrict__ part) {
    __shared__ float S[2 * STRIDE];
    __shared__ float dxs[CHUNK * DIM];
    __shared__ float Z[88];
    const int t = threadIdx.x;
    const int c = blockIdx.x;
    const int j0 = c * CHUNK;
    const int cnt = min(CHUNK, NSEG - j0);

    for (int i = t; i < 2 * STRIDE; i += 256) S[i] = 0.f;
    for (int i = t; i < cnt * DIM; i += 256)
        dxs[i] = x[j0 * DIM + i + DIM] - x[j0 * DIM + i];
    if (t == 0) {
        S[ONE_SLOT] = 1.f; S[STRIDE + ONE_SLOT] = 1.f;
        Z[Z_ONE] = 1.f; Z[Z_ZERO] = 0.f;
    }

    // Precompute per-slot operand indices:
    // new = So[i0] + So[i1]*Z[i2] + Z[i3]*Z[i4]
    int i0[NSLOT], i1[NSLOT], i2[NSLOT], i3[NSLOT], i4[NSLOT];
#pragma unroll
    for (int k = 0; k < NSLOT; ++k) {
        int e = t + 256 * k;
        if (e < 6) {                               // L1: S1 + dx
            i0[k] = e; i1[k] = ONE_SLOT; i2[k] = Z_DX + e;
            i3[k] = Z_ZERO; i4[k] = Z_ZERO;
        } else if (e < 42) {                       // L2: S2 + S1[a]*dx[b] + e2[ab]
            int f = e - 6; int a = f / 6, b = f % 6;
            i0[k] = e; i1[k] = a; i2[k] = Z_DX + b;
            i3[k] = Z_E2 + f; i4[k] = Z_ONE;
        } else if (e < 258) {                      // L3: S3 + S2[ab]*dx[c] + t3[a]*e2[bc]
            int f = e - 42; int ab = f / 6, cc = f % 6, a = f / 36, bc = f % 36;
            i0[k] = e; i1[k] = 6 + ab; i2[k] = Z_DX + cc;
            i3[k] = Z_T3 + a; i4[k] = Z_E2 + bc;
        } else if (e < NSTATE) {                   // L4: S4 + S3[abc]*dx[d] + t2[ab]*e2[cd]
            int f = e - 258; int abc = f / 6, d = f % 6, ab = f / 36, cd = f % 36;
            i0[k] = e; i1[k] = 42 + abc; i2[k] = Z_DX + d;
            i3[k] = Z_T2 + ab; i4[k] = Z_E2 + cd;
        } else {                                   // inactive
            i0[k] = DUMMY_SLOT; i1[k] = ZERO_SLOT; i2[k] = Z_ZERO;
            i3[k] = Z_ZERO; i4[k] = Z_ZERO;
        }
    }
    __syncthreads();

    int po = 0;
    for (int j = 0; j < cnt; ++j) {
        const float* So = S + po * STRIDE;
        float* Sn = S + (po ^ 1) * STRIDE;
        const float* dxj = dxs + j * DIM;
        // Phase A: per-segment helpers (reads old state + dx)
        if (t < 36) {
            int a = t / 6, b = t % 6;
            float da = dxj[a], db = dxj[b];
            Z[Z_E2 + t] = 0.5f * da * db;
            Z[Z_T2 + t] = So[6 + t] + db * (So[a] * (1.f / 3.f) + da * (1.f / 12.f));
        } else if (t < 42) {
            int a = t - 36;
            float dxa = dxj[a];
            Z[Z_T3 + a] = So[a] + dxa * (1.f / 3.f);
            Z[Z_DX + a] = dxa;
        }
        __syncthreads();
        // Phase B: uniform state update
        float nv[NSLOT];
#pragma unroll
        for (int k = 0; k < NSLOT; ++k)
            nv[k] = So[i0[k]] + So[i1[k]] * Z[i2[k]] + Z[i3[k]] * Z[i4[k]];
#pragma unroll
        for (int k = 0; k < NSLOT; ++k)
            Sn[i0[k]] = nv[k];
        po ^= 1;
        __syncthreads();
    }

    const float* Sf = S + po * STRIDE;
    for (int e = t; e < NSTATE; e += 256)
        part[(size_t)c * NSTATE + e] = Sf[e];
}

// ---------------- Kernel B/C: Chen-combine gs consecutive partials ----------
__global__ __launch_bounds__(256) void sig_combine(const float* __restrict__ in,
                                                   float* __restrict__ out, int gs) {
    __shared__ float S[2 * STRIDE];
    const int t = threadIdx.x;
    const int g = blockIdx.x;
    const float* base = in + (size_t)g * gs * NSTATE;

    for (int i = t; i < 2 * STRIDE; i += 256) S[i] = 0.f;
    __syncthreads();
    for (int e = t; e < NSTATE; e += 256) S[e] = base[e];

    // new = So[i0r] + U[iue] + So[p1]*U[q1] + So[p2]*U[q2] + So[p3]*U[q3]
    int i0w[NSLOT], i0r[NSLOT], iue[NSLOT];
    int p1[NSLOT], q1[NSLOT], p2[NSLOT], q2[NSLOT], p3[NSLOT], q3[NSLOT];
#pragma unroll
    for (int k = 0; k < NSLOT; ++k) {
        int e = t + 256 * k;
        if (e < 6) {
            i0w[k] = i0r[k] = e; iue[k] = e;
            p1[k] = ZERO_SLOT; q1[k] = 0; p2[k] = ZERO_SLOT; q2[k] = 0;
            p3[k] = ZERO_SLOT; q3[k] = 0;
        } else if (e < 42) {
            int f = e - 6; int a = f / 6, b = f % 6;
            i0w[k] = i0r[k] = e; iue[k] = e;
            p1[k] = a; q1[k] = b;
            p2[k] = ZERO_SLOT; q2[k] = 0; p3[k] = ZERO_SLOT; q3[k] = 0;
        } else if (e < 258) {
            int f = e - 42; int ab = f / 6, cc = f % 6, a = f / 36, bc = f % 36;
            i0w[k] = i0r[k] = e; iue[k] = e;
            p1[k] = 6 + ab; q1[k] = cc;
            p2[k] = a; q2[k] = 6 + bc;
            p3[k] = ZERO_SLOT; q3[k] = 0;
        } else if (e < NSTATE) {
            int f = e - 258;
            int abc = f / 6, d = f % 6, ab = f / 36, cd = f % 36, a = f / 216, bcd = f % 216;
            i0w[k] = i0r[k] = e; iue[k] = e;
            p1[k] = 42 + abc; q1[k] = d;
            p2[k] = 6 + ab; q2[k] = 6 + cd;
            p3[k] = a; q3[k] = 42 + bcd;
        } else {
            i0w[k] = DUMMY_SLOT; i0r[k] = ZERO_SLOT; iue[k] = 0;
            p1[k] = ZERO_SLOT; q1[k] = 0; p2[k] = ZERO_SLOT; q2[k] = 0;
            p3[k] = ZERO_SLOT; q3[k] = 0;
        }
    }
    __syncthreads();

    int po = 0;
    for (int r = 1; r < gs; ++r) {
        const float* U = base + (size_t)r * NSTATE;
        const float* So = S + po * STRIDE;
        float* Sn = S + (po ^ 1) * STRIDE;
        float nv[NSLOT];
#pragma unroll
        for (int k = 0; k < NSLOT; ++k)
            nv[k] = So[i0r[k]] + U[iue[k]] + So[p1[k]] * U[q1[k]]
                  + So[p2[k]] * U[q2[k]] + So[p3[k]] * U[q3[k]];
#pragma unroll
        for (int k = 0; k < NSLOT; ++k)
            Sn[i0w[k]] = nv[k];
        po ^= 1;
        __syncthreads();
    }

    const float* Sf = S + po * STRIDE;
    for (int e = t; e < NSTATE; e += 256)
        out[(size_t)g * NSTATE + e] = Sf[e];
}

// ---------------------------------------------------------------------------
extern "C" void kernel_launch(void* const* d_in, const int* in_sizes, int n_in,
                              void* d_out, int out_size, void* d_ws, size_t ws_size,
                              hipStream_t stream) {
    const float* x = (const float*)d_in[0];
    float* out = (float*)d_out;
    float* ws0 = (float*)d_ws;                       // 1024 partial signatures
    float* ws1 = ws0 + (size_t)NCHUNK * NSTATE;      // 32 partial signatures

    sig_chunks<<<NCHUNK, 256, 0, stream>>>(x, ws0);
    sig_combine<<<32, 256, 0, stream>>>(ws0, ws1, 32);
    sig_combine<<<1, 256, 0, stream>>>(ws1, out, 32);
}

// Round 2
// 127.652 us; speedup vs baseline: 2.2554x; 2.2554x over previous
//
#include <hip/hip_runtime.h>

#define DIM 6
#define NSTATE 1554      // 6 + 36 + 216 + 1296
#define NSEG 65535
#define CH 64            // segments per chunk
#define NCHUNK 1024      // NCHUNK*CH >= NSEG

// Shared "P buffer" layout (floats), ping-pong x2:
//   S1:  [0,6)      t3: [8,14)     S2: [16,52)    t2: [52,88)
//   S3pad: [88,376)  = 36 rows x 8 (6 used)   -- 16B-aligned rows
//   e2pad: [376,424) = 6 rows x 8             -- 16B-aligned rows
#define OFF_S1 0
#define OFF_T3 8
#define OFF_S2 16
#define OFF_T2 52
#define OFF_S3 88
#define OFF_E2 376
#define PBUF 424

// ---------------- Kernel A: per-chunk signature, register-resident state ----
__global__ __launch_bounds__(256) void sig_chunks(const float* __restrict__ x,
                                                  float* __restrict__ part) {
    __shared__ float dxs[(CH + 1) * 8];   // padded rows of 8, rows >= cnt zeroed
    __shared__ float buf[2][PBUF];
    const int t = threadIdx.x;
    const int c = blockIdx.x;
    const int j0 = c * CH;
    const int cnt = min(CH, NSEG - j0);   // 64, or 63 for the last chunk

    // stage increments (row j = dx of segment j0+j); zero-pad rows >= cnt
    for (int f = t; f < (CH + 1) * DIM; f += 256) {
        int j = f / DIM, k = f - j * DIM;
        float v = 0.f;
        if (j < cnt) v = x[(j0 + j + 1) * DIM + k] - x[(j0 + j) * DIM + k];
        dxs[j * 8 + k] = v;
    }
    __syncthreads();

    // roles:
    //   t < 216          : owns L4 group abc=t  (6 elems in r4)
    //   216 <= t < 252   : owns L3 group f=t-216 (6 elems in r3) and S2[f] (r2)
    //   250 <= t < 256   : owns S1[a], a=t-250 (r1)
    const int ab4 = t / 6, cc4 = t - ab4 * 6;          // L4 decomposition
    const int f3 = t - 216;
    const int a3 = (f3 >= 0) ? f3 / 6 : 0, b3 = (f3 >= 0) ? f3 - a3 * 6 : 0;
    const int a1 = t - 250;

    float r4[6] = {0, 0, 0, 0, 0, 0};
    float r3[6] = {0, 0, 0, 0, 0, 0};
    float r2 = 0.f, r1 = 0.f;

    // init buf[0]: zero state + helpers for segment 0 (uses dx row 0)
    if (t >= 216 && t < 252) {
        float d0a = dxs[a3], d0b = dxs[b3];
        float* Q = buf[0];
#pragma unroll
        for (int d = 0; d < 6; ++d) Q[OFF_S3 + f3 * 8 + d] = 0.f;
        Q[OFF_S2 + f3] = 0.f;
        Q[OFF_T2 + f3] = d0b * d0a * (1.f / 12.f);
        Q[OFF_E2 + a3 * 8 + b3] = 0.5f * d0a * d0b;
    }
    if (t >= 250) {
        buf[0][OFF_S1 + a1] = 0.f;
        buf[0][OFF_T3 + a1] = dxs[a1] * (1.f / 3.f);
    }
    __syncthreads();

    int po = 0;
#pragma unroll 2
    for (int j = 0; j < CH; ++j) {
        const float* P = buf[po];
        float* Q = buf[po ^ 1];
        const float* dxr = dxs + j * 8;
        if (t < 216) {
            // S4' = S4 + S3[abc]*dx[d] + t2[ab]*e2[c][d]
            float s3 = P[OFF_S3 + ab4 * 8 + cc4];
            float t2v = P[OFF_T2 + ab4];
            float e2r[6], dxj[6];
#pragma unroll
            for (int d = 0; d < 6; ++d) e2r[d] = P[OFF_E2 + cc4 * 8 + d];
#pragma unroll
            for (int d = 0; d < 6; ++d) dxj[d] = dxr[d];
#pragma unroll
            for (int d = 0; d < 6; ++d) r4[d] += s3 * dxj[d] + t2v * e2r[d];
        } else if (t < 252) {
            // S3' = S3 + S2[ab]*dx[c] + t3[a]*e2[b][c];  S2' = S2 + S1[a]*dx[b] + e2[a][b]
            float dxj[6];
#pragma unroll
            for (int d = 0; d < 6; ++d) dxj[d] = dxr[d];
            float s2 = P[OFF_S2 + f3];
            float t3v = P[OFF_T3 + a3];
            float s1 = P[OFF_S1 + a3];
            float e2ab = P[OFF_E2 + a3 * 8 + b3];
            float e2r[6];
#pragma unroll
            for (int d = 0; d < 6; ++d) e2r[d] = P[OFF_E2 + b3 * 8 + d];
#pragma unroll
            for (int d = 0; d < 6; ++d) r3[d] += s2 * dxj[d] + t3v * e2r[d];
            r2 += s1 * dxj[b3] + e2ab;
            // publish state + next-segment helpers (dx row j+1)
            float dna = dxs[(j + 1) * 8 + a3];
            float dnb = dxs[(j + 1) * 8 + b3];
#pragma unroll
            for (int d = 0; d < 6; ++d) Q[OFF_S3 + f3 * 8 + d] = r3[d];
            Q[OFF_S2 + f3] = r2;
            float s1n = s1 + dxj[a3];
            Q[OFF_T2 + f3] = r2 + dnb * (s1n * (1.f / 3.f) + dna * (1.f / 12.f));
            Q[OFF_E2 + a3 * 8 + b3] = 0.5f * dna * dnb;
        }
        if (t >= 250) {
            float dja = dxr[a1];
            float dna = dxs[(j + 1) * 8 + a1];
            r1 += dja;
            Q[OFF_S1 + a1] = r1;
            Q[OFF_T3 + a1] = r1 + dna * (1.f / 3.f);
        }
        po ^= 1;
        __syncthreads();
    }

    // write partial signature (flat 1554)
    const size_t base = (size_t)c * NSTATE;
    if (t < 216) {
#pragma unroll
        for (int d = 0; d < 6; ++d) part[base + 258 + t * 6 + d] = r4[d];
    } else if (t < 252) {
#pragma unroll
        for (int d = 0; d < 6; ++d) part[base + 42 + f3 * 6 + d] = r3[d];
        part[base + 6 + f3] = r2;
    }
    if (t >= 250) part[base + a1] = r1;
}

// ---------------- Chen pair-combine of one 6-element output group ----------
// Group g in [0,259): g==0 -> L1; 1..6 -> L2 row a; 7..42 -> L3 row ab;
// 43..258 -> L4 row abc.  A,B,T are flat 1554-float signatures (any addr space).
__device__ __forceinline__ void chen_group(const float* A, const float* B,
                                           float* T, int g) {
    if (g == 0) {
#pragma unroll
        for (int d = 0; d < 6; ++d) T[d] = A[d] + B[d];
    } else if (g < 7) {
        int a = g - 1;
        float a1 = A[a];
        const float* Ar = A + 6 + a * 6;
        const float* Br = B + 6 + a * 6;
        float* Tr = T + 6 + a * 6;
#pragma unroll
        for (int d = 0; d < 6; ++d) Tr[d] = Ar[d] + Br[d] + a1 * B[d];
    } else if (g < 43) {
        int ab = g - 7, a = ab / 6, b = ab - a * 6;
        float a2 = A[6 + ab], a1 = A[a];
        const float* Ar = A + 42 + ab * 6;
        const float* Br = B + 42 + ab * 6;
        const float* B2r = B + 6 + b * 6;
        float* Tr = T + 42 + ab * 6;
#pragma unroll
        for (int d = 0; d < 6; ++d)
            Tr[d] = Ar[d] + Br[d] + a2 * B[d] + a1 * B2r[d];
    } else {
        int abc = g - 43, ab = abc / 6, cc = abc - ab * 6, a = abc / 36,
            bc = abc - a * 36;
        float a3 = A[42 + abc], a2 = A[6 + ab], a1 = A[a];
        const float* Ar = A + 258 + abc * 6;
        const float* Br = B + 258 + abc * 6;
        const float* B2r = B + 6 + cc * 6;
        const float* B3r = B + 42 + bc * 6;
        float* Tr = T + 258 + abc * 6;
#pragma unroll
        for (int d = 0; d < 6; ++d)
            Tr[d] = Ar[d] + Br[d] + a3 * B[d] + a2 * B2r[d] + a1 * B3r[d];
    }
}

// ---------------- Kernel B: radix-gs in-block Chen tree ---------------------
// Block g combines partials [g*gs, (g+1)*gs) -> out[g].  gs in {2, 8}.
__global__ __launch_bounds__(256) void sig_tree(const float* __restrict__ in,
                                                float* __restrict__ out, int gs) {
    __shared__ float buf0[4 * NSTATE];
    __shared__ float buf1[2 * NSTATE];
    const int t = threadIdx.x;
    const float* gbase = in + (size_t)blockIdx.x * gs * NSTATE;
    float* outp = out + (size_t)blockIdx.x * NSTATE;

    int np = gs >> 1;
    {   // level 0: pairs read directly from global (L2-hot)
        float* o = (np == 1) ? outp : buf0;
        for (int idx = t; idx < np * 259; idx += 256) {
            int p = idx / 259, g = idx - p * 259;
            chen_group(gbase + (size_t)(2 * p) * NSTATE,
                       gbase + (size_t)(2 * p + 1) * NSTATE,
                       o + (size_t)p * NSTATE, g);
        }
    }
    float* cur = buf0;
    float* nxt = buf1;
    while (np > 1) {
        __syncthreads();
        np >>= 1;
        float* o = (np == 1) ? outp : nxt;
        for (int idx = t; idx < np * 259; idx += 256) {
            int p = idx / 259, g = idx - p * 259;
            chen_group(cur + (size_t)(2 * p) * NSTATE,
                       cur + (size_t)(2 * p + 1) * NSTATE,
                       o + (size_t)p * NSTATE, g);
        }
        float* tmp = cur; cur = nxt; nxt = tmp;
    }
}

// ---------------------------------------------------------------------------
extern "C" void kernel_launch(void* const* d_in, const int* in_sizes, int n_in,
                              void* d_out, int out_size, void* d_ws, size_t ws_size,
                              hipStream_t stream) {
    const float* x = (const float*)d_in[0];
    float* out = (float*)d_out;
    float* ws0 = (float*)d_ws;                        // 1024 partials
    float* ws1 = ws0 + (size_t)NCHUNK * NSTATE;       // 128 partials
    float* ws2 = ws0;                                 // 16 partials (reuse ws0)
    float* ws3 = ws0 + (size_t)16 * NSTATE;           // 2 partials

    sig_chunks<<<NCHUNK, 256, 0, stream>>>(x, ws0);
    sig_tree<<<128, 256, 0, stream>>>(ws0, ws1, 8);   // 1024 -> 128
    sig_tree<<<16, 256, 0, stream>>>(ws1, ws2, 8);    // 128  -> 16
    sig_tree<<<2, 256, 0, stream>>>(ws2, ws3, 8);     // 16   -> 2
    sig_tree<<<1, 256, 0, stream>>>(ws3, out, 2);     // 2    -> 1
}